// Round 18
// baseline (475.318 us; speedup 1.0000x reference)
//
#include <hip/hip_runtime.h>
#include <hip/hip_bf16.h>
#include <math.h>

#define B_  32
#define L_  1024
#define CIN 3
#define DM  256
#define DI  512
#define NST 16
#define NH  8
#define NC  10
#define M_TOT (B_*L_)
#define NSEG 8
#define SEGT (L_/NSEG)   // 128

typedef unsigned short u16;
typedef __attribute__((ext_vector_type(8))) short bf16x8;
typedef __attribute__((ext_vector_type(4))) float f32x4;
typedef const __attribute__((address_space(1))) unsigned int* gptr_t;
typedef __attribute__((address_space(3))) unsigned int* sptr_t;

static __device__ __forceinline__ float sigmoidf_(float x) {
    return 1.0f / (1.0f + __expf(-x));
}
static __device__ __forceinline__ u16 f2bf(float f) {       // RNE
    unsigned int u = __float_as_uint(f);
    return (u16)((u + 0x7FFF + ((u >> 16) & 1)) >> 16);
}
static __device__ __forceinline__ float bf2f(u16 u) {
    return __uint_as_float(((unsigned int)u) << 16);
}
static __device__ __forceinline__ float2 bf2x2(unsigned int u) {
    return make_float2(bf2f((u16)(u & 0xffff)), bf2f((u16)(u >> 16)));
}
static __device__ __forceinline__ void gload_lds16(const void* g, void* s) {
    __builtin_amdgcn_global_load_lds(
        (gptr_t)(unsigned long long)g,
        (sptr_t)(unsigned int)(unsigned long long)s, 16, 0, 0);
}

// 8-lane sum of 2 values via DPP (v7-proven form).
static __device__ __forceinline__ void reduce8_pair(float& a, float& b) {
    asm volatile(
        "s_nop 1\n\t"
        "v_add_f32 %0, %0, %0 quad_perm:[1,0,3,2] row_mask:0xf bank_mask:0xf\n\t"
        "v_add_f32 %1, %1, %1 quad_perm:[1,0,3,2] row_mask:0xf bank_mask:0xf\n\t"
        "s_nop 1\n\t"
        "v_add_f32 %0, %0, %0 quad_perm:[2,3,0,1] row_mask:0xf bank_mask:0xf\n\t"
        "v_add_f32 %1, %1, %1 quad_perm:[2,3,0,1] row_mask:0xf bank_mask:0xf\n\t"
        "s_nop 1\n\t"
        "v_add_f32 %0, %0, %0 row_half_mirror row_mask:0xf bank_mask:0xf\n\t"
        "v_add_f32 %1, %1, %1 row_half_mirror row_mask:0xf bank_mask:0xf\n\t"
        "s_nop 1\n\t"
        : "+v"(a), "+v"(b));
}

// ---------------- K0: fp32 -> bf16 weight conversion (both weights) --------
__global__ __launch_bounds__(256) void k_cvt2(const float* __restrict__ wi,
        const float* __restrict__ wo, u16* __restrict__ obi,
        u16* __restrict__ obo) {
    int idx = blockIdx.x * 256 + threadIdx.x;
    const float* src;
    u16* dst;
    int i;
    if (idx < (2*DI*DM)/4) { src = wi; dst = obi; i = idx*4; }
    else { src = wo; dst = obo; i = (idx - (2*DI*DM)/4)*4; }
    float4 v = *(const float4*)(src + i);
    ushort4 o;
    o.x = f2bf(v.x); o.y = f2bf(v.y); o.z = f2bf(v.z); o.w = f2bf(v.w);
    *(ushort4*)(dst + i) = o;
}

// ---------------- K1: conv embedding + positional encoding (bf16 out) ------
__global__ __launch_bounds__(256) void k_embed(const float* __restrict__ xe,
        const float* __restrict__ w, u16* __restrict__ x) {
    int bl = blockIdx.x;
    int l = bl & (L_-1);
    int b = bl >> 10;
    int d = threadIdx.x;
    const float* xb = xe + (size_t)b * L_ * CIN;
    int t0 = l > 0 ? l-1 : 0;
    int t2 = l < L_-1 ? l+1 : L_-1;
    const float* w3 = w + d*9;
    float acc = 0.f;
    #pragma unroll
    for (int i = 0; i < 3; ++i) {
        acc += xb[t0*3+i] * w3[i*3+0];
        acc += xb[l *3+i] * w3[i*3+1];
        acc += xb[t2*3+i] * w3[i*3+2];
    }
    int j = d >> 1;
    float div = expf((float)(2*j) * (-logf(10000.0f)/(float)DM));
    float ang = (float)l * div;
    acc += (d & 1) ? cosf(ang) : sinf(ang);
    x[(size_t)bl*DM + d] = f2bf(acc);
}

// ---------------- K2/K7: bf16 MFMA NT GEMM, global_load_lds staging --------
#define BKK 32
__global__ __launch_bounds__(256) void k_gemm_mfma(
        const u16* __restrict__ A, const u16* __restrict__ W,
        float* __restrict__ O1f, u16* __restrict__ O1b,
        u16* __restrict__ O2b, int M, int N, int K, int S) {
    __shared__ u16 As[128*BKK];
    __shared__ u16 Bs[128*BKK];
    int tid = threadIdx.x;
    int row0 = blockIdx.y * 128, col0 = blockIdx.x * 128;
    int wave = tid >> 6, lane = tid & 63;
    int wr = (wave >> 1) * 64, wc = (wave & 1) * 64;
    int l16 = lane & 15, kl = lane >> 4;
    int sr_ = lane >> 2;
    int sc_ = lane & 3;

    f32x4 acc[4][4];
    #pragma unroll
    for (int m = 0; m < 4; ++m)
        #pragma unroll
        for (int n = 0; n < 4; ++n)
            acc[m][n] = (f32x4){0.f, 0.f, 0.f, 0.f};

    for (int k0 = 0; k0 < K; k0 += BKK) {
        __syncthreads();
        #pragma unroll
        for (int t = 0; t < 2; ++t) {
            int r = wave*32 + t*16 + sr_;
            int csw = sc_ ^ ((r >> 2) & 3);
            gload_lds16(A + (size_t)(row0 + r)*K + k0 + csw*8,
                        &As[(wave*32 + t*16)*BKK]);
            gload_lds16(W + (size_t)(col0 + r)*K + k0 + csw*8,
                        &Bs[(wave*32 + t*16)*BKK]);
        }
        __syncthreads();
        bf16x8 af[4], bf[4];
        #pragma unroll
        for (int m = 0; m < 4; ++m) {
            int row = wr + m*16 + l16;
            af[m] = *(const bf16x8*)&As[row*BKK + (kl ^ ((row>>2)&3))*8];
        }
        #pragma unroll
        for (int n = 0; n < 4; ++n) {
            int row = wc + n*16 + l16;
            bf[n] = *(const bf16x8*)&Bs[row*BKK + (kl ^ ((row>>2)&3))*8];
        }
        #pragma unroll
        for (int m = 0; m < 4; ++m)
            #pragma unroll
            for (int n = 0; n < 4; ++n)
                acc[m][n] = __builtin_amdgcn_mfma_f32_16x16x32_bf16(
                                af[m], bf[n], acc[m][n], 0, 0, 0);
    }

    #pragma unroll
    for (int m = 0; m < 4; ++m) {
        int rbase = row0 + wr + m*16 + kl*4;
        #pragma unroll
        for (int n = 0; n < 4; ++n) {
            int col = col0 + wc + n*16 + l16;
            #pragma unroll
            for (int r = 0; r < 4; ++r) {
                float v = acc[m][n][r];
                if (col < S) {
                    if (O1b) O1b[(size_t)(rbase + r)*S + col] = f2bf(v);
                    else     O1f[(size_t)(rbase + r)*S + col] = v;
                } else {
                    O2b[(size_t)(rbase + r)*(N - S) + (col - S)] = f2bf(v);
                }
            }
        }
    }
}

// ---------------- K3: depthwise causal conv1d, bf16 in/out, x4 vec ---------
__global__ __launch_bounds__(256) void k_conv(const u16* __restrict__ xin,
        const float* __restrict__ w, const float* __restrict__ bias,
        u16* __restrict__ xc) {
    size_t i4 = (size_t)blockIdx.x * 256 + threadIdx.x;
    int d4 = (int)(i4 & (DI/4 - 1)) * 4;
    size_t m = i4 >> 7;
    int l = (int)(m & (L_-1));
    float4 wv0 = *(const float4*)(w + (size_t)(d4+0)*4);
    float4 wv1 = *(const float4*)(w + (size_t)(d4+1)*4);
    float4 wv2 = *(const float4*)(w + (size_t)(d4+2)*4);
    float4 wv3 = *(const float4*)(w + (size_t)(d4+3)*4);
    float W[4][4] = {{wv0.x,wv0.y,wv0.z,wv0.w},{wv1.x,wv1.y,wv1.z,wv1.w},
                     {wv2.x,wv2.y,wv2.z,wv2.w},{wv3.x,wv3.y,wv3.z,wv3.w}};
    float4 acc = *(const float4*)(bias + d4);
    #pragma unroll
    for (int k = 0; k < 4; ++k) {
        int t = l + k - 3;
        if (t >= 0) {
            ushort4 xv = *(const ushort4*)(xin + (m + k - 3)*DI + d4);
            acc.x = fmaf(bf2f(xv.x), W[0][k], acc.x);
            acc.y = fmaf(bf2f(xv.y), W[1][k], acc.y);
            acc.z = fmaf(bf2f(xv.z), W[2][k], acc.z);
            acc.w = fmaf(bf2f(xv.w), W[3][k], acc.w);
        }
    }
    ushort4 r;
    r.x = f2bf(acc.x * sigmoidf_(acc.x));
    r.y = f2bf(acc.y * sigmoidf_(acc.y));
    r.z = f2bf(acc.z * sigmoidf_(acc.z));
    r.w = f2bf(acc.w * sigmoidf_(acc.w));
    *(ushort4*)(xc + m*DI + d4) = r;
}

// ---------------- K4: x_proj — tiled GEMM, bf16 A, M x 48, K=512 -----------
#define XBM 128
#define XBK 16
__global__ __launch_bounds__(256) void k_xproj(const u16* __restrict__ xc,
        const float* __restrict__ wp, float* __restrict__ dbl) {
    __shared__ float As[XBK][XBM];
    __shared__ float Ws[XBK][48];
    int tid = threadIdx.x;
    int row0 = blockIdx.x * XBM;
    int lr = tid >> 1;
    int lk = (tid & 1) * 8;
    int we = tid >> 2;
    int wk = (tid & 3) * 4;
    int tx = tid & 15;
    int ty = tid >> 4;
    float acc[8][3];
    #pragma unroll
    for (int i = 0; i < 8; ++i)
        #pragma unroll
        for (int j = 0; j < 3; ++j) acc[i][j] = 0.f;

    for (int k0 = 0; k0 < DI; k0 += XBK) {
        ushort4 ab0 = *(const ushort4*)(xc + (size_t)(row0+lr)*DI + k0 + lk);
        ushort4 ab1 = *(const ushort4*)(xc + (size_t)(row0+lr)*DI + k0 + lk + 4);
        float4 w0 = make_float4(0.f,0.f,0.f,0.f);
        if (tid < 192) w0 = *(const float4*)(wp + (size_t)we*DI + k0 + wk);
        __syncthreads();
        As[lk+0][lr]=bf2f(ab0.x); As[lk+1][lr]=bf2f(ab0.y);
        As[lk+2][lr]=bf2f(ab0.z); As[lk+3][lr]=bf2f(ab0.w);
        As[lk+4][lr]=bf2f(ab1.x); As[lk+5][lr]=bf2f(ab1.y);
        As[lk+6][lr]=bf2f(ab1.z); As[lk+7][lr]=bf2f(ab1.w);
        if (tid < 192) {
            Ws[wk+0][we]=w0.x; Ws[wk+1][we]=w0.y; Ws[wk+2][we]=w0.z; Ws[wk+3][we]=w0.w;
        }
        __syncthreads();
        #pragma unroll
        for (int k = 0; k < XBK; ++k) {
            float4 av0 = *(const float4*)&As[k][ty*8];
            float4 av1 = *(const float4*)&As[k][ty*8+4];
            float w0_ = Ws[k][tx*3+0];
            float w1_ = Ws[k][tx*3+1];
            float w2_ = Ws[k][tx*3+2];
            float ar[8] = {av0.x,av0.y,av0.z,av0.w,av1.x,av1.y,av1.z,av1.w};
            #pragma unroll
            for (int i = 0; i < 8; ++i) {
                acc[i][0] = fmaf(ar[i], w0_, acc[i][0]);
                acc[i][1] = fmaf(ar[i], w1_, acc[i][1]);
                acc[i][2] = fmaf(ar[i], w2_, acc[i][2]);
            }
        }
    }
    #pragma unroll
    for (int i = 0; i < 8; ++i) {
        size_t r = row0 + ty*8 + i;
        #pragma unroll
        for (int j = 0; j < 3; ++j)
            dbl[r*48 + tx*3 + j] = acc[i][j];
    }
}

// ---------------- K5: dt_proj (K=16) + softplus, bf16 out ------------------
__global__ __launch_bounds__(256) void k_dtproj(const float* __restrict__ dbl,
        const float* __restrict__ dtw, const float* __restrict__ dtb,
        u16* __restrict__ dt) {
    __shared__ float wl[DI][17];
    __shared__ float rl[32][16];
    size_t m0 = (size_t)blockIdx.x * 32;
    for (int i = threadIdx.x; i < DI*16; i += 256)
        wl[i >> 4][i & 15] = dtw[i];
    for (int i = threadIdx.x; i < 32*16; i += 256)
        rl[i >> 4][i & 15] = dbl[(m0 + (i>>4))*48 + (i & 15)];
    __syncthreads();
    float b0 = dtb[threadIdx.x];
    float b1 = dtb[256 + threadIdx.x];
    for (int mm = 0; mm < 32; ++mm) {
        #pragma unroll
        for (int half = 0; half < 2; ++half) {
            int d = half*256 + threadIdx.x;
            float acc = half ? b1 : b0;
            #pragma unroll
            for (int r = 0; r < 16; ++r)
                acc = fmaf(rl[mm][r], wl[d][r], acc);
            float sp = fmaxf(acc, 0.f) + log1pf(__expf(-fabsf(acc)));
            dt[(m0+mm)*DI + d] = f2bf(sp);
        }
    }
}

// ---------------- K6a: scan phase A — per-segment (aprod, hfin) ------------
// Block = 32 channels x 1 batch x 1 segment (grid DI/32, B_, NSEG).
// Lane owns 2 states; no cross-lane ops at all. LDS 21.5 KB.
#define SCAN_T 64
__global__ __launch_bounds__(256) void k_scanpre(const u16* __restrict__ dt,
        const u16* __restrict__ xcb, const float* __restrict__ dbl,
        const float* __restrict__ A_log,
        float* __restrict__ aseg, float* __restrict__ hseg) {
    __shared__ float2 sq2[SCAN_T*33];   // [t][ch]: (dt, dt*x)
    __shared__ float2 sBp[SCAN_T*9];    // [t][j]: (B_{2j}, B_{2j+1})

    int tid = threadIdx.x;
    int wave = tid >> 6, lane = tid & 63;
    int chw = lane >> 3;
    int j   = lane & 7;
    int ch  = wave*8 + chw;
    int d0 = blockIdx.x * 32;
    int b  = blockIdx.y;
    int s  = blockIdx.z;
    int d  = d0 + ch;
    float Aa = -expf(A_log[(size_t)d*NST + 2*j])     * 1.44269504f;
    float Ab = -expf(A_log[(size_t)d*NST + 2*j + 1]) * 1.44269504f;
    float h0 = 0.f, h1 = 0.f, ap0 = 1.f, ap1 = 1.f;
    size_t base = (size_t)b * L_;

    int st = tid >> 2;
    int sc = (tid & 3) * 8;
    int ns = (tid & 3) * 4;

    for (int t0 = s*SEGT; t0 < (s+1)*SEGT; t0 += SCAN_T) {
        __syncthreads();
        {
            size_t row = base + t0 + st;
            uint4 dv = *(const uint4*)(dt  + row*DI + d0 + sc);
            uint4 xv = *(const uint4*)(xcb + row*DI + d0 + sc);
            float4 Bv = *(const float4*)(dbl + row*48 + 16 + ns);
            float2 dt01 = bf2x2(dv.x), dt23 = bf2x2(dv.y);
            float2 dt45 = bf2x2(dv.z), dt67 = bf2x2(dv.w);
            float2 x01 = bf2x2(xv.x), x23 = bf2x2(xv.y);
            float2 x45 = bf2x2(xv.z), x67 = bf2x2(xv.w);
            float dtr[8] = { dt01.x, dt01.y, dt23.x, dt23.y,
                             dt45.x, dt45.y, dt67.x, dt67.y };
            float xr[8]  = { x01.x, x01.y, x23.x, x23.y,
                             x45.x, x45.y, x67.x, x67.y };
            #pragma unroll
            for (int k = 0; k < 8; ++k)
                sq2[st*33 + sc + k] = make_float2(dtr[k], dtr[k]*xr[k]);
            sBp[st*9 + ns/2]     = make_float2(Bv.x, Bv.y);
            sBp[st*9 + ns/2 + 1] = make_float2(Bv.z, Bv.w);
        }
        __syncthreads();

        #pragma unroll 4
        for (int t = 0; t < SCAN_T; ++t) {
            float2 q  = sq2[t*33 + ch];
            float2 Bp = sBp[t*9 + j];
            float dA0 = exp2f(q.x * Aa);
            float dA1 = exp2f(q.x * Ab);
            ap0 *= dA0;
            ap1 *= dA1;
            h0 = fmaf(dA0, h0, q.y * Bp.x);
            h1 = fmaf(dA1, h1, q.y * Bp.y);
        }
    }
    size_t oidx = ((((size_t)s*B_ + b)*DI + d)*NST) + 2*j;
    *(float2*)&aseg[oidx] = make_float2(ap0, ap1);
    *(float2*)&hseg[oidx] = make_float2(h0, h1);
}

// ---------------- K6b: scan phase B — prefix over segments (in place) ------
// Thread per (b,d,n). Overwrites hseg[s] with h_init[s].
__global__ __launch_bounds__(256) void k_scanfix(const float* __restrict__ aseg,
        float* __restrict__ hseg) {
    size_t i = (size_t)blockIdx.x*256 + threadIdx.x;   // over B_*DI*NST
    size_t stride = (size_t)B_*DI*NST;
    float hi = 0.f;
    #pragma unroll
    for (int s = 0; s < NSEG; ++s) {
        float a  = aseg[s*stride + i];
        float hf = hseg[s*stride + i];
        hseg[s*stride + i] = hi;
        hi = fmaf(a, hi, hf);
    }
}

// ---------------- K6c: scan phase C — v7 body seeded from h_init -----------
__global__ __launch_bounds__(256) void k_scan(const u16* __restrict__ dt,
        const u16* __restrict__ xcb, const float* __restrict__ dbl,
        const float* __restrict__ A_log, const float* __restrict__ Dp,
        const u16* __restrict__ zbf, const float* __restrict__ hseg,
        u16* __restrict__ ybf) {
    __shared__ float4 sq4[SCAN_T*33];
    __shared__ float2 sBC2[SCAN_T*18];

    int tid = threadIdx.x;
    int wave = tid >> 6, lane = tid & 63;
    int chw = lane >> 3;
    int j   = lane & 7;
    int ch  = wave*8 + chw;
    int d0 = blockIdx.x * 32;
    int b  = blockIdx.y;
    int s  = blockIdx.z;
    int d  = d0 + ch;
    float Aa = -expf(A_log[(size_t)d*NST + 2*j])     * 1.44269504f;
    float Ab = -expf(A_log[(size_t)d*NST + 2*j + 1]) * 1.44269504f;
    size_t oidx = ((((size_t)s*B_ + b)*DI + d)*NST) + 2*j;
    float2 hi = *(const float2*)&hseg[oidx];
    float h0 = hi.x, h1 = hi.y;
    size_t base = (size_t)b * L_;

    int st = tid >> 2;
    int sc = (tid & 3) * 8;
    int ns = (tid & 3) * 4;
    float4 Dva = *(const float4*)(Dp + d0 + sc);
    float4 Dvb = *(const float4*)(Dp + d0 + sc + 4);

    for (int t0 = s*SEGT; t0 < (s+1)*SEGT; t0 += SCAN_T) {
        __syncthreads();
        {
            size_t row = base + t0 + st;
            uint4 dv = *(const uint4*)(dt  + row*DI + d0 + sc);
            uint4 xv = *(const uint4*)(xcb + row*DI + d0 + sc);
            uint4 zv = *(const uint4*)(zbf + row*DI + d0 + sc);
            float4 Bv = *(const float4*)(dbl + row*48 + 16 + ns);
            float4 Cv = *(const float4*)(dbl + row*48 + 32 + ns);
            float2 dt01 = bf2x2(dv.x), dt23 = bf2x2(dv.y);
            float2 dt45 = bf2x2(dv.z), dt67 = bf2x2(dv.w);
            float2 x01 = bf2x2(xv.x), x23 = bf2x2(xv.y);
            float2 x45 = bf2x2(xv.z), x67 = bf2x2(xv.w);
            float2 z01 = bf2x2(zv.x), z23 = bf2x2(zv.y);
            float2 z45 = bf2x2(zv.z), z67 = bf2x2(zv.w);
            float dtr[8] = { dt01.x, dt01.y, dt23.x, dt23.y,
                             dt45.x, dt45.y, dt67.x, dt67.y };
            float xr[8]  = { x01.x, x01.y, x23.x, x23.y,
                             x45.x, x45.y, x67.x, x67.y };
            float zr[8]  = { z01.x, z01.y, z23.x, z23.y,
                             z45.x, z45.y, z67.x, z67.y };
            float Dr[8] = { Dva.x, Dva.y, Dva.z, Dva.w,
                            Dvb.x, Dvb.y, Dvb.z, Dvb.w };
            #pragma unroll
            for (int k = 0; k < 8; ++k) {
                float g = zr[k] * sigmoidf_(zr[k]);
                sq4[st*33 + sc + k] = make_float4(dtr[k], dtr[k]*xr[k],
                                                  xr[k]*Dr[k]*g, g);
            }
            *(float4*)&sBC2[st*18 + ns]     = make_float4(Bv.x, Cv.x, Bv.y, Cv.y);
            *(float4*)&sBC2[st*18 + ns + 2] = make_float4(Bv.z, Cv.z, Bv.w, Cv.w);
        }
        __syncthreads();

        #pragma unroll 2
        for (int t2 = 0; t2 < SCAN_T/2; ++t2) {
            float4 bc0 = *(const float4*)&sBC2[(2*t2)*18 + 2*j];
            float4 bc1 = *(const float4*)&sBC2[(2*t2+1)*18 + 2*j];
            float4 q0 = sq4[(2*t2)*33 + ch];
            float4 q1 = sq4[(2*t2+1)*33 + ch];
            float dA0 = exp2f(q0.x * Aa);
            float dA1 = exp2f(q0.x * Ab);
            h0 = fmaf(dA0, h0, q0.y * bc0.x);
            h1 = fmaf(dA1, h1, q0.y * bc0.z);
            float p0 = fmaf(h1, bc0.w, h0 * bc0.y);
            dA0 = exp2f(q1.x * Aa);
            dA1 = exp2f(q1.x * Ab);
            h0 = fmaf(dA0, h0, q1.y * bc1.x);
            h1 = fmaf(dA1, h1, q1.y * bc1.z);
            float p1 = fmaf(h1, bc1.w, h0 * bc1.y);
            reduce8_pair(p0, p1);
            if (j == 0) {
                size_t row = base + t0 + 2*t2;
                ybf[row*DI + d]     = f2bf(fmaf(p0, q0.w, q0.z));
                ybf[(row+1)*DI + d] = f2bf(fmaf(p1, q1.w, q1.z));
            }
        }
    }
}

// ---------------- K8: fused LayerNorm + silu + 18-col GEMM -----------------
#define HBK 32
__global__ __launch_bounds__(256) void k_lnheads18(const u16* __restrict__ mb,
        const float* __restrict__ g, const float* __restrict__ bta,
        const float* __restrict__ aw, const float* __restrict__ ow,
        float* __restrict__ r18) {
    __shared__ float As[128][36];
    __shared__ float Ws[18][36];
    __shared__ float gb[DM], bb[DM];
    int tid = threadIdx.x;
    int row0 = blockIdx.x * 128;
    int sr = tid >> 1, sk = (tid & 1) * 16;
    gb[tid] = g[tid];
    bb[tid] = bta[tid];
    const u16* mrow = mb + (size_t)(row0 + sr)*DM;

    float s1 = 0.f, s2 = 0.f;
    for (int k0 = 0; k0 < DM; k0 += HBK) {
        uint4 va = *(const uint4*)(mrow + k0 + sk);
        uint4 vb = *(const uint4*)(mrow + k0 + sk + 8);
        unsigned int ua[8] = {va.x, va.y, va.z, va.w, vb.x, vb.y, vb.z, vb.w};
        #pragma unroll
        for (int q = 0; q < 8; ++q) {
            float2 p = bf2x2(ua[q]);
            s1 += p.x + p.y;
            s2 += p.x*p.x + p.y*p.y;
        }
    }
    s1 += __shfl_xor(s1, 1);
    s2 += __shfl_xor(s2, 1);
    float mu = s1 * (1.0f/DM);
    float var = fmaxf(s2 * (1.0f/DM) - mu*mu, 0.f);
    float rstd = 1.0f / sqrtf(var + 1e-5f);

    int r = tid >> 1, cb = (tid & 1) * 9;
    float acc[9];
    #pragma unroll
    for (int c = 0; c < 9; ++c) acc[c] = 0.f;

    for (int k0 = 0; k0 < DM; k0 += HBK) {
        uint4 va = *(const uint4*)(mrow + k0 + sk);
        uint4 vb = *(const uint4*)(mrow + k0 + sk + 8);
        float4 wv = make_float4(0.f,0.f,0.f,0.f);
        int wc = tid >> 3, wk = (tid & 7) * 4;
        if (tid < 144) {
            const float* wsrc = (wc < NH) ? (aw + wc*DM) : (ow + (wc-NH)*DM);
            wv = *(const float4*)(wsrc + k0 + wk);
        }
        __syncthreads();
        {
            unsigned int ua[8] = {va.x, va.y, va.z, va.w, vb.x, vb.y, vb.z, vb.w};
            #pragma unroll
            for (int q = 0; q < 8; ++q) {
                float2 p = bf2x2(ua[q]);
                int c0 = k0 + sk + 2*q;
                float o0 = (p.x - mu)*rstd*gb[c0]   + bb[c0];
                float o1 = (p.y - mu)*rstd*gb[c0+1] + bb[c0+1];
                As[sr][sk + 2*q]     = o0 * sigmoidf_(o0);
                As[sr][sk + 2*q + 1] = o1 * sigmoidf_(o1);
            }
            if (tid < 144)
                *(float4*)&Ws[wc][wk] = wv;
        }
        __syncthreads();
        #pragma unroll
        for (int k4 = 0; k4 < HBK/4; ++k4) {
            float4 av = *(const float4*)&As[r][k4*4];
            #pragma unroll
            for (int c = 0; c < 9; ++c) {
                float4 w4 = *(const float4*)&Ws[cb + c][k4*4];
                acc[c] += av.x*w4.x + av.y*w4.y + av.z*w4.z + av.w*w4.w;
            }
        }
    }
    #pragma unroll
    for (int c = 0; c < 9; ++c)
        r18[(size_t)(row0 + r)*18 + cb + c] = acc[c];
}

// ---------------- K9b: per-b head-max softmax over L + weighted logit sum --
__global__ __launch_bounds__(256) void k_final(const float* __restrict__ r18,
        const float* __restrict__ ab, const float* __restrict__ xmark,
        float* __restrict__ out) {
    __shared__ float e[L_];
    __shared__ float red[256];
    int b = blockIdx.x;
    int tid = threadIdx.x;
    float abr[NH];
    #pragma unroll
    for (int j = 0; j < NH; ++j) abr[j] = ab[j];
    float mx = -1e30f;
    for (int l = tid; l < L_; l += 256) {
        const float* rr = r18 + ((size_t)b*L_ + l)*18;
        float sm = rr[0] + abr[0];
        #pragma unroll
        for (int j = 1; j < NH; ++j) sm = fmaxf(sm, rr[j] + abr[j]);
        e[l] = sm;
        mx = fmaxf(mx, sm);
    }
    #pragma unroll
    for (int o = 32; o > 0; o >>= 1) mx = fmaxf(mx, __shfl_xor(mx, o));
    red[tid] = mx;
    __syncthreads();
    mx = fmaxf(fmaxf(red[0], red[64]), fmaxf(red[128], red[192]));
    __syncthreads();
    float ssum = 0.f;
    for (int l = tid; l < L_; l += 256) {
        float ev = __expf(e[l] - mx);
        e[l] = ev;
        ssum += ev;
    }
    #pragma unroll
    for (int o = 32; o > 0; o >>= 1) ssum += __shfl_xor(ssum, o);
    if ((tid & 63) == 0) red[tid >> 6] = ssum;
    __syncthreads();
    float inv = 1.0f / (red[0]+red[1]+red[2]+red[3]);
    float acc[NC];
    #pragma unroll
    for (int c = 0; c < NC; ++c) acc[c] = 0.f;
    for (int l = tid; l < L_; l += 256) {
        float wl = e[l] * xmark[(size_t)b*L_ + l];
        const float* lg = r18 + ((size_t)b*L_ + l)*18 + NH;
        #pragma unroll
        for (int c = 0; c < NC; ++c) acc[c] = fmaf(wl, lg[c], acc[c]);
    }
    __syncthreads();
    for (int c = 0; c < NC; ++c) {
        red[tid] = acc[c];
        __syncthreads();
        if (tid < 64) {
            float s2 = red[tid]+red[tid+64]+red[tid+128]+red[tid+192];
            #pragma unroll
            for (int o = 32; o > 0; o >>= 1) s2 += __shfl_xor(s2, o);
            if (tid == 0) out[(size_t)b*NC + c] = s2 * inv;
        }
        __syncthreads();
    }
}

extern "C" void kernel_launch(void* const* d_in, const int* in_sizes, int n_in,
                              void* d_out, int out_size, void* d_ws, size_t ws_size,
                              hipStream_t stream) {
    const float* x_enc  = (const float*)d_in[0];
    const float* x_mark = (const float*)d_in[1];
    const float* cemb_w = (const float*)d_in[2];
    const float* inp_w  = (const float*)d_in[3];
    const float* c1_w   = (const float*)d_in[4];
    const float* c1_b   = (const float*)d_in[5];
    const float* xp_w   = (const float*)d_in[6];
    const float* dtp_w  = (const float*)d_in[7];
    const float* dtp_b  = (const float*)d_in[8];
    const float* A_log  = (const float*)d_in[9];
    const float* Dp     = (const float*)d_in[10];
    const float* outp_w = (const float*)d_in[11];
    const float* ln_g   = (const float*)d_in[12];
    const float* ln_b   = (const float*)d_in[13];
    const float* out_w  = (const float*)d_in[14];
    const float* attn_w = (const float*)d_in[15];
    const float* attn_b = (const float*)d_in[16];
    float* out = (float*)d_out;

    char* ws = (char*)d_ws;
    size_t o = 0;
    u16*   xbf  = (u16*)(ws + o);   o += (size_t)M_TOT*DM*2;
    u16*   xinb = (u16*)(ws + o);   o += (size_t)M_TOT*DI*2;
    u16*   zbf  = (u16*)(ws + o);   o += (size_t)M_TOT*DI*2;
    u16*   xcb  = (u16*)(ws + o);   o += (size_t)M_TOT*DI*2;
    u16*   ybf  = (u16*)(ws + o);   o += (size_t)M_TOT*DI*2;
    u16*   dt16 = (u16*)(ws + o);   o += (size_t)M_TOT*DI*2;
    u16*   mm16 = (u16*)(ws + o);   o += (size_t)M_TOT*DM*2;
    float* dbl  = (float*)(ws + o); o += (size_t)M_TOT*48*4;
    u16*   wbfi = (u16*)(ws + o);   o += (size_t)2*DI*DM*2;
    u16*   wbfo = (u16*)(ws + o);   o += (size_t)DM*DI*2;
    float* r18  = (float*)(ws + o); o += (size_t)M_TOT*18*4;
    float* aseg = (float*)(ws + o); o += (size_t)NSEG*B_*DI*NST*4;  // 8.4 MB
    float* hseg = (float*)(ws + o); o += (size_t)NSEG*B_*DI*NST*4;  // 8.4 MB

    k_cvt2  <<<(2*DI*DM + DM*DI)/1024, 256, 0, stream>>>(inp_w, outp_w,
                                                         wbfi, wbfo);
    k_embed <<<M_TOT, 256, 0, stream>>>(x_enc, cemb_w, xbf);
    k_gemm_mfma<<<dim3(8, M_TOT/128), 256, 0, stream>>>(xbf, wbfi,
                                nullptr, xinb, zbf, M_TOT, 2*DI, DM, DI);
    k_conv  <<<(M_TOT*DI/4)/256, 256, 0, stream>>>(xinb, c1_w, c1_b, xcb);
    k_xproj <<<M_TOT/XBM, 256, 0, stream>>>(xcb, xp_w, dbl);
    k_dtproj<<<M_TOT/32, 256, 0, stream>>>(dbl, dtp_w, dtp_b, dt16);
    k_scanpre<<<dim3(DI/32, B_, NSEG), 256, 0, stream>>>(dt16, xcb, dbl,
                                                         A_log, aseg, hseg);
    k_scanfix<<<(B_*DI*NST)/256, 256, 0, stream>>>(aseg, hseg);
    k_scan  <<<dim3(DI/32, B_, NSEG), 256, 0, stream>>>(dt16, xcb, dbl, A_log,
                                                 Dp, zbf, hseg, ybf);
    k_gemm_mfma<<<dim3(2, M_TOT/128), 256, 0, stream>>>(ybf, wbfo,
                                nullptr, mm16, zbf, M_TOT, DM, DI, DM);
    k_lnheads18<<<M_TOT/128, 256, 0, stream>>>(mm16, ln_g, ln_b, attn_w,
                                               out_w, r18);
    k_final <<<B_, 256, 0, stream>>>(r18, attn_b, x_mark, out);
}

// Round 21
// 436.324 us; speedup vs baseline: 1.0894x; 1.0894x over previous
//
#include <hip/hip_runtime.h>
#include <hip/hip_bf16.h>
#include <math.h>

#define B_  32
#define L_  1024
#define CIN 3
#define DM  256
#define DI  512
#define NST 16
#define NH  8
#define NC  10
#define M_TOT (B_*L_)

typedef unsigned short u16;
typedef __attribute__((ext_vector_type(8))) short bf16x8;
typedef __attribute__((ext_vector_type(4))) float f32x4;
typedef const __attribute__((address_space(1))) unsigned int* gptr_t;
typedef __attribute__((address_space(3))) unsigned int* sptr_t;

static __device__ __forceinline__ float sigmoidf_(float x) {
    return 1.0f / (1.0f + __expf(-x));
}
static __device__ __forceinline__ u16 f2bf(float f) {       // RNE
    unsigned int u = __float_as_uint(f);
    return (u16)((u + 0x7FFF + ((u >> 16) & 1)) >> 16);
}
static __device__ __forceinline__ float bf2f(u16 u) {
    return __uint_as_float(((unsigned int)u) << 16);
}
static __device__ __forceinline__ float2 bf2x2(unsigned int u) {
    return make_float2(bf2f((u16)(u & 0xffff)), bf2f((u16)(u >> 16)));
}
// CK-style addrspace casts for global_load_lds (generic->AS1/AS3 via uintptr)
static __device__ __forceinline__ void gload_lds16(const void* g, void* s) {
    __builtin_amdgcn_global_load_lds(
        (gptr_t)(unsigned long long)g,
        (sptr_t)(unsigned int)(unsigned long long)s, 16, 0, 0);
}

// 8-lane sum of 2 values via DPP (v7-proven form).
static __device__ __forceinline__ void reduce8_pair(float& a, float& b) {
    asm volatile(
        "s_nop 1\n\t"
        "v_add_f32 %0, %0, %0 quad_perm:[1,0,3,2] row_mask:0xf bank_mask:0xf\n\t"
        "v_add_f32 %1, %1, %1 quad_perm:[1,0,3,2] row_mask:0xf bank_mask:0xf\n\t"
        "s_nop 1\n\t"
        "v_add_f32 %0, %0, %0 quad_perm:[2,3,0,1] row_mask:0xf bank_mask:0xf\n\t"
        "v_add_f32 %1, %1, %1 quad_perm:[2,3,0,1] row_mask:0xf bank_mask:0xf\n\t"
        "s_nop 1\n\t"
        "v_add_f32 %0, %0, %0 row_half_mirror row_mask:0xf bank_mask:0xf\n\t"
        "v_add_f32 %1, %1, %1 row_half_mirror row_mask:0xf bank_mask:0xf\n\t"
        "s_nop 1\n\t"
        : "+v"(a), "+v"(b));
}

// ---------------- K0: fp32 -> bf16 weight conversion (both weights) --------
__global__ __launch_bounds__(256) void k_cvt2(const float* __restrict__ wi,
        const float* __restrict__ wo, u16* __restrict__ obi,
        u16* __restrict__ obo) {
    int idx = blockIdx.x * 256 + threadIdx.x;
    const float* src;
    u16* dst;
    int i;
    if (idx < (2*DI*DM)/4) { src = wi; dst = obi; i = idx*4; }
    else { src = wo; dst = obo; i = (idx - (2*DI*DM)/4)*4; }
    float4 v = *(const float4*)(src + i);
    ushort4 o;
    o.x = f2bf(v.x); o.y = f2bf(v.y); o.z = f2bf(v.z); o.w = f2bf(v.w);
    *(ushort4*)(dst + i) = o;
}

// ---------------- K1: conv embedding + positional encoding (bf16 out) ------
__global__ __launch_bounds__(256) void k_embed(const float* __restrict__ xe,
        const float* __restrict__ w, u16* __restrict__ x) {
    int bl = blockIdx.x;
    int l = bl & (L_-1);
    int b = bl >> 10;
    int d = threadIdx.x;
    const float* xb = xe + (size_t)b * L_ * CIN;
    int t0 = l > 0 ? l-1 : 0;
    int t2 = l < L_-1 ? l+1 : L_-1;
    const float* w3 = w + d*9;
    float acc = 0.f;
    #pragma unroll
    for (int i = 0; i < 3; ++i) {
        acc += xb[t0*3+i] * w3[i*3+0];
        acc += xb[l *3+i] * w3[i*3+1];
        acc += xb[t2*3+i] * w3[i*3+2];
    }
    int j = d >> 1;
    float div = expf((float)(2*j) * (-logf(10000.0f)/(float)DM));
    float ang = (float)l * div;
    acc += (d & 1) ? cosf(ang) : sinf(ang);
    x[(size_t)bl*DM + d] = f2bf(acc);
}

// ---------------- K2/K7: bf16 MFMA NT GEMM, global_load_lds staging --------
// Linear [row][32] u16 LDS (64B rows, no pad). XOR swizzle: LDS slot (r,c)
// holds global chunk c ^ ((r>>2)&3); reads apply the same XOR -> 2-way bank
// aliasing (free). Staging: 4 async gload_lds16 per wave per k-iter.
#define BKK 32
__global__ __launch_bounds__(256) void k_gemm_mfma(
        const u16* __restrict__ A, const u16* __restrict__ W,
        float* __restrict__ O1f, u16* __restrict__ O1b,
        u16* __restrict__ O2b, int M, int N, int K, int S) {
    __shared__ u16 As[128*BKK];
    __shared__ u16 Bs[128*BKK];
    int tid = threadIdx.x;
    int row0 = blockIdx.y * 128, col0 = blockIdx.x * 128;
    int wave = tid >> 6, lane = tid & 63;
    int wr = (wave >> 1) * 64, wc = (wave & 1) * 64;
    int l16 = lane & 15, kl = lane >> 4;
    int sr_ = lane >> 2;            // staging row within 16-row chunk
    int sc_ = lane & 3;             // staging k-chunk 0..3 (8 u16 each)

    f32x4 acc[4][4];
    #pragma unroll
    for (int m = 0; m < 4; ++m)
        #pragma unroll
        for (int n = 0; n < 4; ++n)
            acc[m][n] = (f32x4){0.f, 0.f, 0.f, 0.f};

    for (int k0 = 0; k0 < K; k0 += BKK) {
        __syncthreads();   // prior fragment reads done before LDS overwrite
        #pragma unroll
        for (int t = 0; t < 2; ++t) {
            int r = wave*32 + t*16 + sr_;
            int csw = sc_ ^ ((r >> 2) & 3);
            gload_lds16(A + (size_t)(row0 + r)*K + k0 + csw*8,
                        &As[(wave*32 + t*16)*BKK]);
            gload_lds16(W + (size_t)(col0 + r)*K + k0 + csw*8,
                        &Bs[(wave*32 + t*16)*BKK]);
        }
        __syncthreads();   // compiler drains vmcnt(0) before this barrier
        bf16x8 af[4], bf[4];
        #pragma unroll
        for (int m = 0; m < 4; ++m) {
            int row = wr + m*16 + l16;
            af[m] = *(const bf16x8*)&As[row*BKK + (kl ^ ((row>>2)&3))*8];
        }
        #pragma unroll
        for (int n = 0; n < 4; ++n) {
            int row = wc + n*16 + l16;
            bf[n] = *(const bf16x8*)&Bs[row*BKK + (kl ^ ((row>>2)&3))*8];
        }
        #pragma unroll
        for (int m = 0; m < 4; ++m)
            #pragma unroll
            for (int n = 0; n < 4; ++n)
                acc[m][n] = __builtin_amdgcn_mfma_f32_16x16x32_bf16(
                                af[m], bf[n], acc[m][n], 0, 0, 0);
    }

    #pragma unroll
    for (int m = 0; m < 4; ++m) {
        int rbase = row0 + wr + m*16 + kl*4;
        #pragma unroll
        for (int n = 0; n < 4; ++n) {
            int col = col0 + wc + n*16 + l16;
            #pragma unroll
            for (int r = 0; r < 4; ++r) {
                float v = acc[m][n][r];
                if (col < S) {
                    if (O1b) O1b[(size_t)(rbase + r)*S + col] = f2bf(v);
                    else     O1f[(size_t)(rbase + r)*S + col] = v;
                } else {
                    O2b[(size_t)(rbase + r)*(N - S) + (col - S)] = f2bf(v);
                }
            }
        }
    }
}

// ---------------- K3: depthwise causal conv1d, bf16 in/out, x4 vec ---------
__global__ __launch_bounds__(256) void k_conv(const u16* __restrict__ xin,
        const float* __restrict__ w, const float* __restrict__ bias,
        u16* __restrict__ xc) {
    size_t i4 = (size_t)blockIdx.x * 256 + threadIdx.x;   // over M_TOT*DI/4
    int d4 = (int)(i4 & (DI/4 - 1)) * 4;
    size_t m = i4 >> 7;
    int l = (int)(m & (L_-1));
    float4 wv0 = *(const float4*)(w + (size_t)(d4+0)*4);
    float4 wv1 = *(const float4*)(w + (size_t)(d4+1)*4);
    float4 wv2 = *(const float4*)(w + (size_t)(d4+2)*4);
    float4 wv3 = *(const float4*)(w + (size_t)(d4+3)*4);
    float W[4][4] = {{wv0.x,wv0.y,wv0.z,wv0.w},{wv1.x,wv1.y,wv1.z,wv1.w},
                     {wv2.x,wv2.y,wv2.z,wv2.w},{wv3.x,wv3.y,wv3.z,wv3.w}};
    float4 acc = *(const float4*)(bias + d4);
    #pragma unroll
    for (int k = 0; k < 4; ++k) {
        int t = l + k - 3;
        if (t >= 0) {
            ushort4 xv = *(const ushort4*)(xin + (m + k - 3)*DI + d4);
            acc.x = fmaf(bf2f(xv.x), W[0][k], acc.x);
            acc.y = fmaf(bf2f(xv.y), W[1][k], acc.y);
            acc.z = fmaf(bf2f(xv.z), W[2][k], acc.z);
            acc.w = fmaf(bf2f(xv.w), W[3][k], acc.w);
        }
    }
    ushort4 r;
    r.x = f2bf(acc.x * sigmoidf_(acc.x));
    r.y = f2bf(acc.y * sigmoidf_(acc.y));
    r.z = f2bf(acc.z * sigmoidf_(acc.z));
    r.w = f2bf(acc.w * sigmoidf_(acc.w));
    *(ushort4*)(xc + m*DI + d4) = r;
}

// ---------------- K4: x_proj — tiled GEMM, bf16 A, M x 48, K=512 -----------
#define XBM 128
#define XBK 16
__global__ __launch_bounds__(256) void k_xproj(const u16* __restrict__ xc,
        const float* __restrict__ wp, float* __restrict__ dbl) {
    __shared__ float As[XBK][XBM];
    __shared__ float Ws[XBK][48];
    int tid = threadIdx.x;
    int row0 = blockIdx.x * XBM;
    int lr = tid >> 1;
    int lk = (tid & 1) * 8;
    int we = tid >> 2;
    int wk = (tid & 3) * 4;
    int tx = tid & 15;
    int ty = tid >> 4;
    float acc[8][3];
    #pragma unroll
    for (int i = 0; i < 8; ++i)
        #pragma unroll
        for (int j = 0; j < 3; ++j) acc[i][j] = 0.f;

    for (int k0 = 0; k0 < DI; k0 += XBK) {
        ushort4 ab0 = *(const ushort4*)(xc + (size_t)(row0+lr)*DI + k0 + lk);
        ushort4 ab1 = *(const ushort4*)(xc + (size_t)(row0+lr)*DI + k0 + lk + 4);
        float4 w0 = make_float4(0.f,0.f,0.f,0.f);
        if (tid < 192) w0 = *(const float4*)(wp + (size_t)we*DI + k0 + wk);
        __syncthreads();
        As[lk+0][lr]=bf2f(ab0.x); As[lk+1][lr]=bf2f(ab0.y);
        As[lk+2][lr]=bf2f(ab0.z); As[lk+3][lr]=bf2f(ab0.w);
        As[lk+4][lr]=bf2f(ab1.x); As[lk+5][lr]=bf2f(ab1.y);
        As[lk+6][lr]=bf2f(ab1.z); As[lk+7][lr]=bf2f(ab1.w);
        if (tid < 192) {
            Ws[wk+0][we]=w0.x; Ws[wk+1][we]=w0.y; Ws[wk+2][we]=w0.z; Ws[wk+3][we]=w0.w;
        }
        __syncthreads();
        #pragma unroll
        for (int k = 0; k < XBK; ++k) {
            float4 av0 = *(const float4*)&As[k][ty*8];
            float4 av1 = *(const float4*)&As[k][ty*8+4];
            float w0_ = Ws[k][tx*3+0];
            float w1_ = Ws[k][tx*3+1];
            float w2_ = Ws[k][tx*3+2];
            float ar[8] = {av0.x,av0.y,av0.z,av0.w,av1.x,av1.y,av1.z,av1.w};
            #pragma unroll
            for (int i = 0; i < 8; ++i) {
                acc[i][0] = fmaf(ar[i], w0_, acc[i][0]);
                acc[i][1] = fmaf(ar[i], w1_, acc[i][1]);
                acc[i][2] = fmaf(ar[i], w2_, acc[i][2]);
            }
        }
    }
    #pragma unroll
    for (int i = 0; i < 8; ++i) {
        size_t r = row0 + ty*8 + i;
        #pragma unroll
        for (int j = 0; j < 3; ++j)
            dbl[r*48 + tx*3 + j] = acc[i][j];
    }
}

// ---------------- K5: dt_proj (K=16) + softplus, bf16 out ------------------
__global__ __launch_bounds__(256) void k_dtproj(const float* __restrict__ dbl,
        const float* __restrict__ dtw, const float* __restrict__ dtb,
        u16* __restrict__ dt) {
    __shared__ float wl[DI][17];
    __shared__ float rl[32][16];
    size_t m0 = (size_t)blockIdx.x * 32;
    for (int i = threadIdx.x; i < DI*16; i += 256)
        wl[i >> 4][i & 15] = dtw[i];
    for (int i = threadIdx.x; i < 32*16; i += 256)
        rl[i >> 4][i & 15] = dbl[(m0 + (i>>4))*48 + (i & 15)];
    __syncthreads();
    float b0 = dtb[threadIdx.x];
    float b1 = dtb[256 + threadIdx.x];
    for (int mm = 0; mm < 32; ++mm) {
        #pragma unroll
        for (int half = 0; half < 2; ++half) {
            int d = half*256 + threadIdx.x;
            float acc = half ? b1 : b0;
            #pragma unroll
            for (int r = 0; r < 16; ++r)
                acc = fmaf(rl[mm][r], wl[d][r], acc);
            float sp = fmaxf(acc, 0.f) + log1pf(__expf(-fabsf(acc)));
            dt[(m0+mm)*DI + d] = f2bf(sp);
        }
    }
}

// ---------------- K6: selective scan v7 — 2 states/lane, 8-lane reduce -----
#define SCAN_T 64
__global__ __launch_bounds__(256) void k_scan(const u16* __restrict__ dt,
        const u16* __restrict__ xcb, const float* __restrict__ dbl,
        const float* __restrict__ A_log, const float* __restrict__ Dp,
        const u16* __restrict__ zbf, u16* __restrict__ ybf) {
    __shared__ float4 sq4[SCAN_T*33];     // [t][ch 0..31, pad]: dt, dt*x, x*D*g, g
    __shared__ float2 sBC2[SCAN_T*18];    // [t][n]: (B_n, C_n), stride 18

    int tid = threadIdx.x;
    int wave = tid >> 6, lane = tid & 63;
    int chw = lane >> 3;
    int j   = lane & 7;
    int ch  = wave*8 + chw;
    int d0 = blockIdx.x * 32;
    int b  = blockIdx.y;
    int d  = d0 + ch;
    float Aa = -expf(A_log[(size_t)d*NST + 2*j])     * 1.44269504f;
    float Ab = -expf(A_log[(size_t)d*NST + 2*j + 1]) * 1.44269504f;
    float h0 = 0.f, h1 = 0.f;
    size_t base = (size_t)b * L_;

    int st = tid >> 2;
    int sc = (tid & 3) * 8;
    int ns = (tid & 3) * 4;
    float4 Dva = *(const float4*)(Dp + d0 + sc);
    float4 Dvb = *(const float4*)(Dp + d0 + sc + 4);

    for (int t0 = 0; t0 < L_; t0 += SCAN_T) {
        __syncthreads();
        {
            size_t row = base + t0 + st;
            uint4 dv = *(const uint4*)(dt  + row*DI + d0 + sc);   // 8 bf16
            uint4 xv = *(const uint4*)(xcb + row*DI + d0 + sc);
            uint4 zv = *(const uint4*)(zbf + row*DI + d0 + sc);
            float4 Bv = *(const float4*)(dbl + row*48 + 16 + ns);
            float4 Cv = *(const float4*)(dbl + row*48 + 32 + ns);
            float2 dt01 = bf2x2(dv.x), dt23 = bf2x2(dv.y);
            float2 dt45 = bf2x2(dv.z), dt67 = bf2x2(dv.w);
            float2 x01 = bf2x2(xv.x), x23 = bf2x2(xv.y);
            float2 x45 = bf2x2(xv.z), x67 = bf2x2(xv.w);
            float2 z01 = bf2x2(zv.x), z23 = bf2x2(zv.y);
            float2 z45 = bf2x2(zv.z), z67 = bf2x2(zv.w);
            float dtr[8] = { dt01.x, dt01.y, dt23.x, dt23.y,
                             dt45.x, dt45.y, dt67.x, dt67.y };
            float xr[8]  = { x01.x, x01.y, x23.x, x23.y,
                             x45.x, x45.y, x67.x, x67.y };
            float zr[8]  = { z01.x, z01.y, z23.x, z23.y,
                             z45.x, z45.y, z67.x, z67.y };
            float Dr[8] = { Dva.x, Dva.y, Dva.z, Dva.w,
                            Dvb.x, Dvb.y, Dvb.z, Dvb.w };
            #pragma unroll
            for (int k = 0; k < 8; ++k) {
                float g = zr[k] * sigmoidf_(zr[k]);
                sq4[st*33 + sc + k] = make_float4(dtr[k], dtr[k]*xr[k],
                                                  xr[k]*Dr[k]*g, g);
            }
            *(float4*)&sBC2[st*18 + ns]     = make_float4(Bv.x, Cv.x, Bv.y, Cv.y);
            *(float4*)&sBC2[st*18 + ns + 2] = make_float4(Bv.z, Cv.z, Bv.w, Cv.w);
        }
        __syncthreads();

        #pragma unroll 2
        for (int t2 = 0; t2 < SCAN_T/2; ++t2) {
            float4 bc0 = *(const float4*)&sBC2[(2*t2)*18 + 2*j];
            float4 bc1 = *(const float4*)&sBC2[(2*t2+1)*18 + 2*j];
            float4 q0 = sq4[(2*t2)*33 + ch];
            float4 q1 = sq4[(2*t2+1)*33 + ch];
            float dA0 = exp2f(q0.x * Aa);
            float dA1 = exp2f(q0.x * Ab);
            h0 = fmaf(dA0, h0, q0.y * bc0.x);
            h1 = fmaf(dA1, h1, q0.y * bc0.z);
            float p0 = fmaf(h1, bc0.w, h0 * bc0.y);
            dA0 = exp2f(q1.x * Aa);
            dA1 = exp2f(q1.x * Ab);
            h0 = fmaf(dA0, h0, q1.y * bc1.x);
            h1 = fmaf(dA1, h1, q1.y * bc1.z);
            float p1 = fmaf(h1, bc1.w, h0 * bc1.y);
            reduce8_pair(p0, p1);
            if (j == 0) {
                size_t row = base + t0 + 2*t2;
                ybf[row*DI + d]     = f2bf(fmaf(p0, q0.w, q0.z));
                ybf[(row+1)*DI + d] = f2bf(fmaf(p1, q1.w, q1.z));
            }
        }
    }
}

// ---------------- K8: fused LayerNorm + silu + 18-col GEMM -----------------
#define HBK 32
__global__ __launch_bounds__(256) void k_lnheads18(const u16* __restrict__ mb,
        const float* __restrict__ g, const float* __restrict__ bta,
        const float* __restrict__ aw, const float* __restrict__ ow,
        float* __restrict__ r18) {
    __shared__ float As[128][36];
    __shared__ float Ws[18][36];
    __shared__ float gb[DM], bb[DM];
    int tid = threadIdx.x;
    int row0 = blockIdx.x * 128;
    int sr = tid >> 1, sk = (tid & 1) * 16;
    gb[tid] = g[tid];
    bb[tid] = bta[tid];
    const u16* mrow = mb + (size_t)(row0 + sr)*DM;

    float s1 = 0.f, s2 = 0.f;
    for (int k0 = 0; k0 < DM; k0 += HBK) {
        uint4 va = *(const uint4*)(mrow + k0 + sk);
        uint4 vb = *(const uint4*)(mrow + k0 + sk + 8);
        unsigned int ua[8] = {va.x, va.y, va.z, va.w, vb.x, vb.y, vb.z, vb.w};
        #pragma unroll
        for (int q = 0; q < 8; ++q) {
            float2 p = bf2x2(ua[q]);
            s1 += p.x + p.y;
            s2 += p.x*p.x + p.y*p.y;
        }
    }
    s1 += __shfl_xor(s1, 1);
    s2 += __shfl_xor(s2, 1);
    float mu = s1 * (1.0f/DM);
    float var = fmaxf(s2 * (1.0f/DM) - mu*mu, 0.f);
    float rstd = 1.0f / sqrtf(var + 1e-5f);

    int r = tid >> 1, cb = (tid & 1) * 9;
    float acc[9];
    #pragma unroll
    for (int c = 0; c < 9; ++c) acc[c] = 0.f;

    for (int k0 = 0; k0 < DM; k0 += HBK) {
        uint4 va = *(const uint4*)(mrow + k0 + sk);
        uint4 vb = *(const uint4*)(mrow + k0 + sk + 8);
        float4 wv = make_float4(0.f,0.f,0.f,0.f);
        int wc = tid >> 3, wk = (tid & 7) * 4;
        if (tid < 144) {
            const float* wsrc = (wc < NH) ? (aw + wc*DM) : (ow + (wc-NH)*DM);
            wv = *(const float4*)(wsrc + k0 + wk);
        }
        __syncthreads();
        {
            unsigned int ua[8] = {va.x, va.y, va.z, va.w, vb.x, vb.y, vb.z, vb.w};
            #pragma unroll
            for (int q = 0; q < 8; ++q) {
                float2 p = bf2x2(ua[q]);
                int c0 = k0 + sk + 2*q;
                float o0 = (p.x - mu)*rstd*gb[c0]   + bb[c0];
                float o1 = (p.y - mu)*rstd*gb[c0+1] + bb[c0+1];
                As[sr][sk + 2*q]     = o0 * sigmoidf_(o0);
                As[sr][sk + 2*q + 1] = o1 * sigmoidf_(o1);
            }
            if (tid < 144)
                *(float4*)&Ws[wc][wk] = wv;
        }
        __syncthreads();
        #pragma unroll
        for (int k4 = 0; k4 < HBK/4; ++k4) {
            float4 av = *(const float4*)&As[r][k4*4];
            #pragma unroll
            for (int c = 0; c < 9; ++c) {
                float4 w4 = *(const float4*)&Ws[cb + c][k4*4];
                acc[c] += av.x*w4.x + av.y*w4.y + av.z*w4.z + av.w*w4.w;
            }
        }
    }
    #pragma unroll
    for (int c = 0; c < 9; ++c)
        r18[(size_t)(row0 + r)*18 + cb + c] = acc[c];
}

// ---------------- K9b: per-b head-max softmax over L + weighted logit sum --
__global__ __launch_bounds__(256) void k_final(const float* __restrict__ r18,
        const float* __restrict__ ab, const float* __restrict__ xmark,
        float* __restrict__ out) {
    __shared__ float e[L_];
    __shared__ float red[256];
    int b = blockIdx.x;
    int tid = threadIdx.x;
    float abr[NH];
    #pragma unroll
    for (int j = 0; j < NH; ++j) abr[j] = ab[j];
    float mx = -1e30f;
    for (int l = tid; l < L_; l += 256) {
        const float* rr = r18 + ((size_t)b*L_ + l)*18;
        float sm = rr[0] + abr[0];
        #pragma unroll
        for (int j = 1; j < NH; ++j) sm = fmaxf(sm, rr[j] + abr[j]);
        e[l] = sm;
        mx = fmaxf(mx, sm);
    }
    #pragma unroll
    for (int o = 32; o > 0; o >>= 1) mx = fmaxf(mx, __shfl_xor(mx, o));
    red[tid] = mx;
    __syncthreads();
    mx = fmaxf(fmaxf(red[0], red[64]), fmaxf(red[128], red[192]));
    __syncthreads();
    float ssum = 0.f;
    for (int l = tid; l < L_; l += 256) {
        float ev = __expf(e[l] - mx);
        e[l] = ev;
        ssum += ev;
    }
    #pragma unroll
    for (int o = 32; o > 0; o >>= 1) ssum += __shfl_xor(ssum, o);
    if ((tid & 63) == 0) red[tid >> 6] = ssum;
    __syncthreads();
    float inv = 1.0f / (red[0]+red[1]+red[2]+red[3]);
    float acc[NC];
    #pragma unroll
    for (int c = 0; c < NC; ++c) acc[c] = 0.f;
    for (int l = tid; l < L_; l += 256) {
        float wl = e[l] * xmark[(size_t)b*L_ + l];
        const float* lg = r18 + ((size_t)b*L_ + l)*18 + NH;
        #pragma unroll
        for (int c = 0; c < NC; ++c) acc[c] = fmaf(wl, lg[c], acc[c]);
    }
    __syncthreads();
    for (int c = 0; c < NC; ++c) {
        red[tid] = acc[c];
        __syncthreads();
        if (tid < 64) {
            float s2 = red[tid]+red[tid+64]+red[tid+128]+red[tid+192];
            #pragma unroll
            for (int o = 32; o > 0; o >>= 1) s2 += __shfl_xor(s2, o);
            if (tid == 0) out[(size_t)b*NC + c] = s2 * inv;
        }
        __syncthreads();
    }
}

extern "C" void kernel_launch(void* const* d_in, const int* in_sizes, int n_in,
                              void* d_out, int out_size, void* d_ws, size_t ws_size,
                              hipStream_t stream) {
    const float* x_enc  = (const float*)d_in[0];
    const float* x_mark = (const float*)d_in[1];
    const float* cemb_w = (const float*)d_in[2];
    const float* inp_w  = (const float*)d_in[3];
    const float* c1_w   = (const float*)d_in[4];
    const float* c1_b   = (const float*)d_in[5];
    const float* xp_w   = (const float*)d_in[6];
    const float* dtp_w  = (const float*)d_in[7];
    const float* dtp_b  = (const float*)d_in[8];
    const float* A_log  = (const float*)d_in[9];
    const float* Dp     = (const float*)d_in[10];
    const float* outp_w = (const float*)d_in[11];
    const float* ln_g   = (const float*)d_in[12];
    const float* ln_b   = (const float*)d_in[13];
    const float* out_w  = (const float*)d_in[14];
    const float* attn_w = (const float*)d_in[15];
    const float* attn_b = (const float*)d_in[16];
    float* out = (float*)d_out;

    char* ws = (char*)d_ws;
    size_t o = 0;
    u16*   xbf  = (u16*)(ws + o);   o += (size_t)M_TOT*DM*2;
    u16*   xinb = (u16*)(ws + o);   o += (size_t)M_TOT*DI*2;
    u16*   zbf  = (u16*)(ws + o);   o += (size_t)M_TOT*DI*2;
    u16*   xcb  = (u16*)(ws + o);   o += (size_t)M_TOT*DI*2;
    u16*   ybf  = (u16*)(ws + o);   o += (size_t)M_TOT*DI*2;
    u16*   dt16 = (u16*)(ws + o);   o += (size_t)M_TOT*DI*2;
    u16*   mm16 = (u16*)(ws + o);   o += (size_t)M_TOT*DM*2;
    float* dbl  = (float*)(ws + o); o += (size_t)M_TOT*48*4;
    u16*   wbfi = (u16*)(ws + o);   o += (size_t)2*DI*DM*2;
    u16*   wbfo = (u16*)(ws + o);   o += (size_t)DM*DI*2;
    float* r18  = (float*)(ws + o); o += (size_t)M_TOT*18*4;

    k_cvt2  <<<(2*DI*DM + DM*DI)/1024, 256, 0, stream>>>(inp_w, outp_w,
                                                         wbfi, wbfo);
    k_embed <<<M_TOT, 256, 0, stream>>>(x_enc, cemb_w, xbf);
    k_gemm_mfma<<<dim3(8, M_TOT/128), 256, 0, stream>>>(xbf, wbfi,
                                nullptr, xinb, zbf, M_TOT, 2*DI, DM, DI);
    k_conv  <<<(M_TOT*DI/4)/256, 256, 0, stream>>>(xinb, c1_w, c1_b, xcb);
    k_xproj <<<M_TOT/XBM, 256, 0, stream>>>(xcb, xp_w, dbl);
    k_dtproj<<<M_TOT/32, 256, 0, stream>>>(dbl, dtp_w, dtp_b, dt16);
    k_scan  <<<dim3(DI/32, B_), 256, 0, stream>>>(dt16, xcb, dbl, A_log, Dp,
                                                  zbf, ybf);
    k_gemm_mfma<<<dim3(2, M_TOT/128), 256, 0, stream>>>(ybf, wbfo,
                                nullptr, mm16, zbf, M_TOT, DM, DI, DM);
    k_lnheads18<<<M_TOT/128, 256, 0, stream>>>(mm16, ln_g, ln_b, attn_w,
                                               out_w, r18);
    k_final <<<B_, 256, 0, stream>>>(r18, attn_b, x_mark, out);
}